// Round 15
// baseline (386.572 us; speedup 1.0000x reference)
//
#include <hip/hip_runtime.h>
#include <hip/hip_bf16.h>
#include <math.h>

#define NN 50000
#define NE 800000
#define CURPAD 16   // one cursor per 64B line
#define CAP 64      // per-node slot capacity; P(deg>=65 | Poisson(16)) ~ 3e-20
// IN=128, HID=16, HEADS=4, OUT=40, H=64

// ---------------- MFMA GEMM: h = x @ W^T (+ fused BN, attn logits) ----------------
using short8 = __attribute__((ext_vector_type(8))) short;
using f32x4  = __attribute__((ext_vector_type(4))) float;

__device__ inline short bfbits(float f) {
    __hip_bfloat16 b = __float2bfloat16(f);   // RNE
    return __builtin_bit_cast(short, b);
}
__device__ inline short8 cvt8(float4 lo, float4 hi) {
    short8 r;
    r[0] = bfbits(lo.x); r[1] = bfbits(lo.y); r[2] = bfbits(lo.z); r[3] = bfbits(lo.w);
    r[4] = bfbits(hi.x); r[5] = bfbits(hi.y); r[6] = bfbits(hi.z); r[7] = bfbits(hi.w);
    return r;
}

// FUSESCAT: blocks [0, scat_blocks) run the single-pass slot scatter FIRST
// (8 edges/thread = 8 independent atomic chains); MFMA waves backfill behind.
template<int K, int CT, int COUT, int HEADSN, bool FUSESCAT>
__global__ __launch_bounds__(256) void mfma_gemm(
    const float* __restrict__ x, const float* __restrict__ W,
    const float* __restrict__ a_src, const float* __restrict__ a_dst,
    const float* __restrict__ bnsc, const float* __restrict__ bnsh,
    ushort* __restrict__ h, float* __restrict__ as_out, float* __restrict__ ad_out,
    int n, int scat_blocks,
    const int* __restrict__ esrc, const int* __restrict__ edst,
    int* __restrict__ cnt, unsigned* __restrict__ pk2)
{
    if (FUSESCAT && (int)blockIdx.x < scat_blocks) {
        int base = ((int)blockIdx.x * 256 + (int)threadIdx.x) * 8;
        int d[8], sv[8], pv[8];
#pragma unroll
        for (int j = 0; j < 8; j++) {
            d[j] = (base + j < NE) ? edst[base + j] : -1;
            sv[j] = (base + j < NE) ? esrc[base + j] : 0;
        }
#pragma unroll
        for (int j = 0; j < 8; j++)
            pv[j] = (d[j] >= 0) ? atomicAdd(&cnt[(size_t)d[j] * CURPAD], 1) : 0;
#pragma unroll
        for (int j = 0; j < 8; j++)
            if (d[j] >= 0 && pv[j] < CAP)
                pk2[((size_t)d[j] << 6) + pv[j]] = (unsigned)sv[j];
        return;
    }

    int bid = (int)blockIdx.x - (FUSESCAT ? scat_blocks : 0);
    int tid = threadIdx.x;
    int w = tid >> 6, l = tid & 63;
    int l15 = l & 15, g = l >> 4;
    int m_base = bid * 64 + w * 16;

    f32x4 acc[CT];
#pragma unroll
    for (int ct = 0; ct < CT; ct++) acc[ct] = f32x4{0.f, 0.f, 0.f, 0.f};

    int arow = m_base + l15; if (arow >= n) arow = n - 1;
    const float* xrow = x + (size_t)arow * K;

#pragma unroll
    for (int ks = 0; ks < K / 32; ks++) {
        int k0 = ks * 32 + g * 8;
        float4 lo = *(const float4*)(xrow + k0);
        float4 hi = *(const float4*)(xrow + k0 + 4);
        if (bnsc) {
            float4 s0 = *(const float4*)(bnsc + k0), s1 = *(const float4*)(bnsc + k0 + 4);
            float4 t0 = *(const float4*)(bnsh + k0), t1 = *(const float4*)(bnsh + k0 + 4);
            lo.x = lo.x * s0.x + t0.x; lo.y = lo.y * s0.y + t0.y;
            lo.z = lo.z * s0.z + t0.z; lo.w = lo.w * s0.w + t0.w;
            hi.x = hi.x * s1.x + t1.x; hi.y = hi.y * s1.y + t1.y;
            hi.z = hi.z * s1.z + t1.z; hi.w = hi.w * s1.w + t1.w;
        }
        short8 a = cvt8(lo, hi);
#pragma unroll
        for (int ct = 0; ct < CT; ct++) {
            int wrow = ct * 16 + l15;
            if (wrow >= COUT) wrow = COUT - 1;
            const float* Wr = W + (size_t)wrow * K;
            float4 blo = *(const float4*)(Wr + k0);
            float4 bhi = *(const float4*)(Wr + k0 + 4);
            short8 b = cvt8(blo, bhi);
            acc[ct] = __builtin_amdgcn_mfma_f32_16x16x32_bf16(a, b, acc[ct], 0, 0, 0);
        }
    }

#pragma unroll
    for (int ct = 0; ct < CT; ct++) {
#pragma unroll
        for (int r = 0; r < 4; r++) {
            int row = m_base + g * 4 + r;
            int col = ct * 16 + l15;
            if (row < n && col < COUT)
                h[(size_t)row * COUT + col] = (ushort)bfbits(acc[ct][r]);
        }
    }

    if (HEADSN == 4) {
        float asv[CT], adv[CT];
#pragma unroll
        for (int ct = 0; ct < CT; ct++) {
            asv[ct] = a_src[ct * 16 + l15];
            adv[ct] = a_dst[ct * 16 + l15];
        }
#pragma unroll
        for (int r = 0; r < 4; r++) {
            float rs[CT], rd[CT];
#pragma unroll
            for (int ct = 0; ct < CT; ct++) {
                rs[ct] = acc[ct][r] * asv[ct];
                rd[ct] = acc[ct][r] * adv[ct];
            }
#pragma unroll
            for (int off = 1; off < 16; off <<= 1) {
#pragma unroll
                for (int ct = 0; ct < CT; ct++) {
                    rs[ct] += __shfl_xor(rs[ct], off);
                    rd[ct] += __shfl_xor(rd[ct], off);
                }
            }
            int row = m_base + g * 4 + r;
            if (row < n) {
#pragma unroll
                for (int ct = 0; ct < CT; ct++) {
                    if (l15 == ct) {
                        as_out[row * 4 + ct] = rs[ct];
                        ad_out[row * 4 + ct] = rd[ct];
                    }
                }
            }
        }
    } else {
        float asv[CT], adv[CT];
#pragma unroll
        for (int ct = 0; ct < CT; ct++) {
            int col = ct * 16 + l15;
            asv[ct] = (col < COUT) ? a_src[col] : 0.f;
            adv[ct] = (col < COUT) ? a_dst[col] : 0.f;
        }
#pragma unroll
        for (int r = 0; r < 4; r++) {
            float rs = 0.f, rd = 0.f;
#pragma unroll
            for (int ct = 0; ct < CT; ct++) {
                rs += acc[ct][r] * asv[ct];
                rd += acc[ct][r] * adv[ct];
            }
#pragma unroll
            for (int off = 1; off < 16; off <<= 1) {
                rs += __shfl_xor(rs, off);
                rd += __shfl_xor(rd, off);
            }
            int row = m_base + g * 4 + r;
            if (row < n && l15 == 0) {
                as_out[row] = rs;
                ad_out[row] = rd;
            }
        }
    }
}

__device__ inline float bfh(unsigned u, bool hi) {
    return __uint_as_float(hi ? (u & 0xffff0000u) : ((u & 0xffffu) << 16));
}

// ---------------- node-centric GAT aggregation, 16 edges in flight ----------------
// sub = lane&3 (16 bf16 channels via 2 uint4 loads), eslot = lane>>2 (16 slots).
// Weights inline: (s, as[s]) prefetched one iteration ahead. f64 accumulators
// keep the fp32-rounded result invariant to the (nondeterministic) slot
// permutation. BNP: block-level BN partial stats fused into the epilogue.
// Requires n % 4 == 0 and grid == n/4 (all waves own a valid node).
template<int CH, int HEADSN, bool LSM, bool BNP>
__global__ __launch_bounds__(256) void gat_kernel(
    const ushort* __restrict__ h, const float* __restrict__ as,
    const float* __restrict__ ad, const int* __restrict__ cnt,
    const unsigned* __restrict__ pk2, const float* __restrict__ bias,
    float* __restrict__ out, float* __restrict__ psum, float* __restrict__ psq,
    int n)
{
    __shared__ float lsv[4][64];
    int tid = threadIdx.x;
    int w = tid >> 6;
    int wid = blockIdx.x * 4 + w;     // < n by construction
    int lane = tid & 63;
    int sub = lane & 3, eslot = lane >> 2;
    int c0 = sub * 16;
    bool act0 = (c0 < CH), act1 = (c0 + 8 < CH);
    int hd = (HEADSN == 1) ? 0 : sub;          // 16 ch per head
    float adi = ad[wid * HEADSN + hd];

    double acc[16];
#pragma unroll
    for (int j = 0; j < 16; j++) acc[j] = 0.0;
    double ss = 0.0;

    int deg = cnt[(size_t)wid * CURPAD];
    if (deg > CAP) deg = CAP;
    int slotbase = wid << 6;
    int nit = (deg + 15) >> 4;
    int pos = eslot;
    bool ok = pos < deg;
    int s = 0; float av = 0.f;
    if (ok) { s = (int)pk2[slotbase + pos]; av = as[s * HEADSN + hd]; }
    for (int it = 0; it < nit; ++it) {
        int posn = pos + 16;
        bool ok2 = (it + 1 < nit) && (posn < deg);
        int s2 = 0; float av2 = 0.f;
        if (ok2) { s2 = (int)pk2[slotbase + posn]; av2 = as[s2 * HEADSN + hd]; }
        float p = 0.f;
        if (ok) {
            float lg = av + adi;
            lg = (lg > 0.f) ? lg : 0.2f * lg;          // leaky_relu 0.2
            p = __expf(fminf(lg, 60.f));
        }
        uint4 ua = make_uint4(0, 0, 0, 0), ub = ua;
        if (act0) ua = *(const uint4*)&h[(size_t)s * CH + c0];
        if (act1) ub = *(const uint4*)&h[(size_t)s * CH + c0 + 8];
        ss += (double)p;                      // p==0 on tail slots -> no-op
        acc[0] += (double)p * (double)bfh(ua.x, 0); acc[1] += (double)p * (double)bfh(ua.x, 1);
        acc[2] += (double)p * (double)bfh(ua.y, 0); acc[3] += (double)p * (double)bfh(ua.y, 1);
        acc[4] += (double)p * (double)bfh(ua.z, 0); acc[5] += (double)p * (double)bfh(ua.z, 1);
        acc[6] += (double)p * (double)bfh(ua.w, 0); acc[7] += (double)p * (double)bfh(ua.w, 1);
        acc[8] += (double)p * (double)bfh(ub.x, 0); acc[9] += (double)p * (double)bfh(ub.x, 1);
        acc[10] += (double)p * (double)bfh(ub.y, 0); acc[11] += (double)p * (double)bfh(ub.y, 1);
        acc[12] += (double)p * (double)bfh(ub.z, 0); acc[13] += (double)p * (double)bfh(ub.z, 1);
        acc[14] += (double)p * (double)bfh(ub.w, 0); acc[15] += (double)p * (double)bfh(ub.w, 1);
        s = s2; av = av2; ok = ok2; pos = posn;
    }

    // combine the 16 edge slots (lane bits 2..5)
#pragma unroll
    for (int o = 4; o <= 32; o <<= 1) {
        ss += __shfl_xor(ss, o);
#pragma unroll
        for (int j = 0; j < 16; j++) acc[j] += __shfl_xor(acc[j], o);
    }

    {   // self-loop
        float lg = as[wid * HEADSN + hd] + adi;
        lg = (lg > 0.f) ? lg : 0.2f * lg;
        float ps = __expf(fminf(lg, 60.f));
        ss += (double)ps;
        uint4 ua = make_uint4(0, 0, 0, 0), ub = ua;
        if (act0) ua = *(const uint4*)&h[(size_t)wid * CH + c0];
        if (act1) ub = *(const uint4*)&h[(size_t)wid * CH + c0 + 8];
        acc[0] += (double)ps * (double)bfh(ua.x, 0); acc[1] += (double)ps * (double)bfh(ua.x, 1);
        acc[2] += (double)ps * (double)bfh(ua.y, 0); acc[3] += (double)ps * (double)bfh(ua.y, 1);
        acc[4] += (double)ps * (double)bfh(ua.z, 0); acc[5] += (double)ps * (double)bfh(ua.z, 1);
        acc[6] += (double)ps * (double)bfh(ua.w, 0); acc[7] += (double)ps * (double)bfh(ua.w, 1);
        acc[8] += (double)ps * (double)bfh(ub.x, 0); acc[9] += (double)ps * (double)bfh(ub.x, 1);
        acc[10] += (double)ps * (double)bfh(ub.y, 0); acc[11] += (double)ps * (double)bfh(ub.y, 1);
        acc[12] += (double)ps * (double)bfh(ub.z, 0); acc[13] += (double)ps * (double)bfh(ub.z, 1);
        acc[14] += (double)ps * (double)bfh(ub.w, 0); acc[15] += (double)ps * (double)bfh(ub.w, 1);
    }

    double inv = 1.0 / (ss + 1e-16);
    float v[16];
    float4 bv[4];
#pragma unroll
    for (int k = 0; k < 4; k++) {
        bool a = (k < 2) ? act0 : act1;
        bv[k] = a ? *(const float4*)&bias[c0 + k * 4] : make_float4(0.f, 0.f, 0.f, 0.f);
    }
#pragma unroll
    for (int j = 0; j < 16; j++)
        v[j] = (float)(acc[j] * inv) + ((const float*)bv)[j];

    if (BNP) {
        if (eslot == 0) {
#pragma unroll
            for (int j = 0; j < 16; j++) lsv[w][c0 + j] = v[j];
        }
        __syncthreads();
        if (tid < 64) {
            float sV = lsv[0][tid] + lsv[1][tid] + lsv[2][tid] + lsv[3][tid];
            float sQ = lsv[0][tid] * lsv[0][tid] + lsv[1][tid] * lsv[1][tid]
                     + lsv[2][tid] * lsv[2][tid] + lsv[3][tid] * lsv[3][tid];
            psum[(size_t)blockIdx.x * 64 + tid] = sV;
            psq[(size_t)blockIdx.x * 64 + tid]  = sQ;
        }
    }

    if (LSM) {
        // log_softmax over CH channels; 16 ch per sub lane, valid per 8-group
        float mx = -INFINITY;
#pragma unroll
        for (int j = 0; j < 16; j++)
            if ((j < 8) ? act0 : act1) mx = fmaxf(mx, v[j]);
        for (int o = 2; o >= 1; o >>= 1) mx = fmaxf(mx, __shfl_xor(mx, o));
        float sse = 0.f;
#pragma unroll
        for (int j = 0; j < 16; j++)
            if ((j < 8) ? act0 : act1) sse += __expf(v[j] - mx);
        for (int o = 2; o >= 1; o >>= 1) sse += __shfl_xor(sse, o);
        float ls = logf(sse);
        if (eslot == 0) {
#pragma unroll
            for (int k = 0; k < 4; k++) {
                bool a = (k < 2) ? act0 : act1;
                if (a) {
                    float4 r = make_float4(v[k*4] - mx - ls, v[k*4+1] - mx - ls,
                                           v[k*4+2] - mx - ls, v[k*4+3] - mx - ls);
                    *(float4*)&out[(size_t)wid * CH + c0 + k * 4] = r;
                    float4 emb = make_float4(v[k*4], v[k*4+1], v[k*4+2], v[k*4+3]);
                    *(float4*)&out[(size_t)n * CH + (size_t)wid * CH + c0 + k * 4] = emb;
                }
            }
        }
    } else {
        if (eslot == 0) {
#pragma unroll
            for (int k = 0; k < 4; k++) {
                bool a = (k < 2) ? act0 : act1;
                if (a)
                    *(float4*)&out[(size_t)wid * CH + c0 + k * 4] =
                        make_float4(v[k*4], v[k*4+1], v[k*4+2], v[k*4+3]);
            }
        }
    }
}

// ---------------- BN reduce: 64 blocks (one per channel), deterministic ----------------
__global__ __launch_bounds__(256) void bn_reduce(
    const float* __restrict__ psum, const float* __restrict__ psq,
    const float* __restrict__ g, const float* __restrict__ bt,
    float* __restrict__ sc, float* __restrict__ sh, int nb, int n)
{
    int c = blockIdx.x;
    int t = threadIdx.x;
    float s = 0.f, s2 = 0.f;
    for (int r = t; r < nb; r += 256) {      // fixed order per thread
        s  += psum[(size_t)r * 64 + c];
        s2 += psq[(size_t)r * 64 + c];
    }
    __shared__ float a[256], b[256];
    a[t] = s; b[t] = s2; __syncthreads();
    for (int o = 128; o >= 1; o >>= 1) {     // fixed tree
        if (t < o) { a[t] += a[t + o]; b[t] += b[t + o]; }
        __syncthreads();
    }
    if (t == 0) {
        float mean = a[0] / n;
        float var = b[0] / n - mean * mean;   // biased, matches torch BN
        float invs = rsqrtf(var + 1e-5f);
        float scale = g[c] * invs;
        sc[c] = scale;
        sh[c] = bt[c] - mean * scale;
    }
}

extern "C" void kernel_launch(void* const* d_in, const int* in_sizes, int n_in,
                              void* d_out, int out_size, void* d_ws, size_t ws_size,
                              hipStream_t stream) {
    const float* x   = (const float*)d_in[0];
    const int*   ei  = (const int*)d_in[1];
    const float* W0  = (const float*)d_in[2];
    const float* as0 = (const float*)d_in[3];
    const float* ad0 = (const float*)d_in[4];
    const float* b0  = (const float*)d_in[5];
    const float* W1  = (const float*)d_in[6];
    const float* as1 = (const float*)d_in[7];
    const float* ad1 = (const float*)d_in[8];
    const float* b1  = (const float*)d_in[9];
    const float* W2  = (const float*)d_in[10];
    const float* as2 = (const float*)d_in[11];
    const float* ad2 = (const float*)d_in[12];
    const float* b2  = (const float*)d_in[13];
    const float* g0  = (const float*)d_in[14];
    const float* bt0 = (const float*)d_in[15];
    const float* g1  = (const float*)d_in[16];
    const float* bt1 = (const float*)d_in[17];

    const int* esrc = ei;
    const int* edst = ei + NE;

    char* ws = (char*)d_ws;
    size_t off = 0;
    auto alloc = [&](size_t bytes) {
        void* p = ws + off;
        off += (bytes + 255) & ~(size_t)255;
        return p;
    };
    int* cnt      = (int*)alloc((size_t)NN * CURPAD * 4);
    unsigned* pk2 = (unsigned*)alloc((size_t)NN * CAP * 4);
    ushort* hbuf  = (ushort*)alloc((size_t)NN * 64 * 2);
    float* obuf   = (float*)alloc((size_t)NN * 64 * 4);
    float* asb    = (float*)alloc((size_t)NN * 4 * 4);
    float* adb    = (float*)alloc((size_t)NN * 4 * 4);
    float* psum   = (float*)alloc((size_t)(NN / 4) * 64 * 4);
    float* psq    = (float*)alloc((size_t)(NN / 4) * 64 * 4);
    float* sc     = (float*)alloc(64 * 4);
    float* sh     = (float*)alloc(64 * 4);

    const int SCB = (NE + 2047) / 2048;          // 391 scatter blocks
    const int GBM = (NN + 63) / 64;              // 782 gemm blocks
    const int GB4 = NN / 4;                      // 12500 gat blocks (NN % 4 == 0)

    // zero cursors, then fused {slot scatter (first) ∥ gemm0}
    hipMemsetAsync(cnt, 0, (size_t)NN * CURPAD * 4, stream);
    mfma_gemm<128, 4, 64, 4, true><<<SCB + GBM, 256, 0, stream>>>(
        x, W0, as0, ad0, nullptr, nullptr, hbuf, asb, adb, NN, SCB,
        esrc, edst, cnt, pk2);

    // Layer 0 aggregation + BN0 partials
    gat_kernel<64, 4, false, true><<<GB4, 256, 0, stream>>>(
        hbuf, asb, adb, cnt, pk2, b0, obuf, psum, psq, NN);
    bn_reduce<<<64, 256, 0, stream>>>(psum, psq, g0, bt0, sc, sh, GB4, NN);

    // Layer 1 (BN0 fused into A-load)
    mfma_gemm<64, 4, 64, 4, false><<<GBM, 256, 0, stream>>>(
        obuf, W1, as1, ad1, sc, sh, hbuf, asb, adb, NN, 0,
        nullptr, nullptr, nullptr, nullptr);
    gat_kernel<64, 4, false, true><<<GB4, 256, 0, stream>>>(
        hbuf, asb, adb, cnt, pk2, b1, obuf, psum, psq, NN);
    bn_reduce<<<64, 256, 0, stream>>>(psum, psq, g1, bt1, sc, sh, GB4, NN);

    // Layer 2 (BN1 fused into A-load); log_softmax fused in gat epilogue
    mfma_gemm<64, 3, 40, 1, false><<<GBM, 256, 0, stream>>>(
        obuf, W2, as2, ad2, sc, sh, hbuf, asb, adb, NN, 0,
        nullptr, nullptr, nullptr, nullptr);
    gat_kernel<40, 1, true, false><<<GB4, 256, 0, stream>>>(
        hbuf, asb, adb, cnt, pk2, b2, (float*)d_out, nullptr, nullptr, NN);
}

// Round 16
// 252.787 us; speedup vs baseline: 1.5292x; 1.5292x over previous
//
#include <hip/hip_runtime.h>
#include <hip/hip_bf16.h>
#include <math.h>

#define NN 50000
#define NE 800000
#define CURPAD 16   // one cursor per 64B line
#define CAP 64      // per-node slot capacity; P(deg>=65 | Poisson(16)) ~ 3e-20
// IN=128, HID=16, HEADS=4, OUT=40, H=64

// ---------------- MFMA GEMM: h = x @ W^T (+ fused BN, attn logits) ----------------
using short8 = __attribute__((ext_vector_type(8))) short;
using f32x4  = __attribute__((ext_vector_type(4))) float;

__device__ inline short bfbits(float f) {
    __hip_bfloat16 b = __float2bfloat16(f);   // RNE
    return __builtin_bit_cast(short, b);
}
__device__ inline short8 cvt8(float4 lo, float4 hi) {
    short8 r;
    r[0] = bfbits(lo.x); r[1] = bfbits(lo.y); r[2] = bfbits(lo.z); r[3] = bfbits(lo.w);
    r[4] = bfbits(hi.x); r[5] = bfbits(hi.y); r[6] = bfbits(hi.z); r[7] = bfbits(hi.w);
    return r;
}

// FUSESCAT: blocks [0, scat_blocks) run the single-pass slot scatter FIRST
// (8 edges/thread = 8 independent atomic chains); MFMA waves backfill behind.
template<int K, int CT, int COUT, int HEADSN, bool FUSESCAT>
__global__ __launch_bounds__(256) void mfma_gemm(
    const float* __restrict__ x, const float* __restrict__ W,
    const float* __restrict__ a_src, const float* __restrict__ a_dst,
    const float* __restrict__ bnsc, const float* __restrict__ bnsh,
    ushort* __restrict__ h, float* __restrict__ as_out, float* __restrict__ ad_out,
    int n, int scat_blocks,
    const int* __restrict__ esrc, const int* __restrict__ edst,
    int* __restrict__ cnt, unsigned* __restrict__ pk2)
{
    if (FUSESCAT && (int)blockIdx.x < scat_blocks) {
        int base = ((int)blockIdx.x * 256 + (int)threadIdx.x) * 8;
        int d[8], sv[8], pv[8];
#pragma unroll
        for (int j = 0; j < 8; j++) {
            d[j] = (base + j < NE) ? edst[base + j] : -1;
            sv[j] = (base + j < NE) ? esrc[base + j] : 0;
        }
#pragma unroll
        for (int j = 0; j < 8; j++)
            pv[j] = (d[j] >= 0) ? atomicAdd(&cnt[(size_t)d[j] * CURPAD], 1) : 0;
#pragma unroll
        for (int j = 0; j < 8; j++)
            if (d[j] >= 0 && pv[j] < CAP)
                pk2[((size_t)d[j] << 6) + pv[j]] = (unsigned)sv[j];
        return;
    }

    int bid = (int)blockIdx.x - (FUSESCAT ? scat_blocks : 0);
    int tid = threadIdx.x;
    int w = tid >> 6, l = tid & 63;
    int l15 = l & 15, g = l >> 4;
    int m_base = bid * 64 + w * 16;

    f32x4 acc[CT];
#pragma unroll
    for (int ct = 0; ct < CT; ct++) acc[ct] = f32x4{0.f, 0.f, 0.f, 0.f};

    int arow = m_base + l15; if (arow >= n) arow = n - 1;
    const float* xrow = x + (size_t)arow * K;

#pragma unroll
    for (int ks = 0; ks < K / 32; ks++) {
        int k0 = ks * 32 + g * 8;
        float4 lo = *(const float4*)(xrow + k0);
        float4 hi = *(const float4*)(xrow + k0 + 4);
        if (bnsc) {
            float4 s0 = *(const float4*)(bnsc + k0), s1 = *(const float4*)(bnsc + k0 + 4);
            float4 t0 = *(const float4*)(bnsh + k0), t1 = *(const float4*)(bnsh + k0 + 4);
            lo.x = lo.x * s0.x + t0.x; lo.y = lo.y * s0.y + t0.y;
            lo.z = lo.z * s0.z + t0.z; lo.w = lo.w * s0.w + t0.w;
            hi.x = hi.x * s1.x + t1.x; hi.y = hi.y * s1.y + t1.y;
            hi.z = hi.z * s1.z + t1.z; hi.w = hi.w * s1.w + t1.w;
        }
        short8 a = cvt8(lo, hi);
#pragma unroll
        for (int ct = 0; ct < CT; ct++) {
            int wrow = ct * 16 + l15;
            if (wrow >= COUT) wrow = COUT - 1;
            const float* Wr = W + (size_t)wrow * K;
            float4 blo = *(const float4*)(Wr + k0);
            float4 bhi = *(const float4*)(Wr + k0 + 4);
            short8 b = cvt8(blo, bhi);
            acc[ct] = __builtin_amdgcn_mfma_f32_16x16x32_bf16(a, b, acc[ct], 0, 0, 0);
        }
    }

#pragma unroll
    for (int ct = 0; ct < CT; ct++) {
#pragma unroll
        for (int r = 0; r < 4; r++) {
            int row = m_base + g * 4 + r;
            int col = ct * 16 + l15;
            if (row < n && col < COUT)
                h[(size_t)row * COUT + col] = (ushort)bfbits(acc[ct][r]);
        }
    }

    if (HEADSN == 4) {
        float asv[CT], adv[CT];
#pragma unroll
        for (int ct = 0; ct < CT; ct++) {
            asv[ct] = a_src[ct * 16 + l15];
            adv[ct] = a_dst[ct * 16 + l15];
        }
#pragma unroll
        for (int r = 0; r < 4; r++) {
            float rs[CT], rd[CT];
#pragma unroll
            for (int ct = 0; ct < CT; ct++) {
                rs[ct] = acc[ct][r] * asv[ct];
                rd[ct] = acc[ct][r] * adv[ct];
            }
#pragma unroll
            for (int off = 1; off < 16; off <<= 1) {
#pragma unroll
                for (int ct = 0; ct < CT; ct++) {
                    rs[ct] += __shfl_xor(rs[ct], off);
                    rd[ct] += __shfl_xor(rd[ct], off);
                }
            }
            int row = m_base + g * 4 + r;
            if (row < n) {
#pragma unroll
                for (int ct = 0; ct < CT; ct++) {
                    if (l15 == ct) {
                        as_out[row * 4 + ct] = rs[ct];
                        ad_out[row * 4 + ct] = rd[ct];
                    }
                }
            }
        }
    } else {
        float asv[CT], adv[CT];
#pragma unroll
        for (int ct = 0; ct < CT; ct++) {
            int col = ct * 16 + l15;
            asv[ct] = (col < COUT) ? a_src[col] : 0.f;
            adv[ct] = (col < COUT) ? a_dst[col] : 0.f;
        }
#pragma unroll
        for (int r = 0; r < 4; r++) {
            float rs = 0.f, rd = 0.f;
#pragma unroll
            for (int ct = 0; ct < CT; ct++) {
                rs += acc[ct][r] * asv[ct];
                rd += acc[ct][r] * adv[ct];
            }
#pragma unroll
            for (int off = 1; off < 16; off <<= 1) {
                rs += __shfl_xor(rs, off);
                rd += __shfl_xor(rd, off);
            }
            int row = m_base + g * 4 + r;
            if (row < n && l15 == 0) {
                as_out[row] = rs;
                ad_out[row] = rd;
            }
        }
    }
}

// ---------------- node-centric GAT aggregation, 8 edges in flight ----------------
// sub = lane&7 (8 bf16 channels via one uint4 load), eslot = lane>>3.
// Weights inline: (s, as[s]) prefetched one iteration ahead. f32 accumulators:
// plain positive-weighted sum of <=65 terms — replay-order variation perturbs
// the result by ~1e-6 relative, far inside the 0.095 absmax threshold (no
// rescale chains, no float atomics anywhere downstream). BNP: block-level BN
// partial stats in the epilogue. Requires n % 4 == 0 and grid == n/4.
template<int CH, int HEADSN, bool LSM, bool BNP>
__global__ __launch_bounds__(256) void gat_kernel(
    const ushort* __restrict__ h, const float* __restrict__ as,
    const float* __restrict__ ad, const int* __restrict__ cnt,
    const unsigned* __restrict__ pk2, const float* __restrict__ bias,
    float* __restrict__ out, float* __restrict__ psum, float* __restrict__ psq,
    int n)
{
    __shared__ float lsv[4][64];
    int tid = threadIdx.x;
    int w = tid >> 6;
    int wid = blockIdx.x * 4 + w;          // < n by construction
    int lane = tid & 63;
    int sub = lane & 7, eslot = lane >> 3;
    int c0 = sub * 8;
    bool act = (c0 < CH);
    int hd = (HEADSN == 1) ? 0 : (sub >> 1);
    float adi = ad[wid * HEADSN + hd];

    float ac0 = 0.f, ac1 = 0.f, ac2 = 0.f, ac3 = 0.f;
    float ac4 = 0.f, ac5 = 0.f, ac6 = 0.f, ac7 = 0.f;
    float ss = 0.f;

    int deg = cnt[(size_t)wid * CURPAD];
    if (deg > CAP) deg = CAP;
    int slotbase = wid << 6;
    int nit = (deg + 7) >> 3;
    int pos = eslot;
    bool ok = pos < deg;
    int s = 0; float av = 0.f;
    if (ok) { s = (int)pk2[slotbase + pos]; av = as[s * HEADSN + hd]; }
    for (int it = 0; it < nit; ++it) {
        int posn = pos + 8;
        bool ok2 = (it + 1 < nit) && (posn < deg);
        int s2 = 0; float av2 = 0.f;
        if (ok2) { s2 = (int)pk2[slotbase + posn]; av2 = as[s2 * HEADSN + hd]; }
        float p = 0.f;
        if (ok) {
            float lg = av + adi;
            lg = (lg > 0.f) ? lg : 0.2f * lg;          // leaky_relu 0.2
            p = __expf(fminf(lg, 60.f));
        }
        float h0 = 0.f, h1 = 0.f, h2 = 0.f, h3 = 0.f, h4 = 0.f, h5 = 0.f, h6 = 0.f, h7 = 0.f;
        if (act) {
            uint4 u = *(const uint4*)&h[(size_t)s * CH + c0];   // 8 x bf16
            h0 = __uint_as_float((u.x & 0xffffu) << 16);
            h1 = __uint_as_float(u.x & 0xffff0000u);
            h2 = __uint_as_float((u.y & 0xffffu) << 16);
            h3 = __uint_as_float(u.y & 0xffff0000u);
            h4 = __uint_as_float((u.z & 0xffffu) << 16);
            h5 = __uint_as_float(u.z & 0xffff0000u);
            h6 = __uint_as_float((u.w & 0xffffu) << 16);
            h7 = __uint_as_float(u.w & 0xffff0000u);
        }
        ss += p;                              // p==0 on tail slots -> no-op
        ac0 += p * h0;  ac1 += p * h1;  ac2 += p * h2;  ac3 += p * h3;
        ac4 += p * h4;  ac5 += p * h5;  ac6 += p * h6;  ac7 += p * h7;
        s = s2; av = av2; ok = ok2; pos = posn;
    }

    // combine the 8 edge slots (lane bits 3,4,5)
#pragma unroll
    for (int o = 8; o <= 32; o <<= 1) {
        ss  += __shfl_xor(ss, o);
        ac0 += __shfl_xor(ac0, o);  ac1 += __shfl_xor(ac1, o);
        ac2 += __shfl_xor(ac2, o);  ac3 += __shfl_xor(ac3, o);
        ac4 += __shfl_xor(ac4, o);  ac5 += __shfl_xor(ac5, o);
        ac6 += __shfl_xor(ac6, o);  ac7 += __shfl_xor(ac7, o);
    }

    {   // self-loop
        float lg = as[wid * HEADSN + hd] + adi;
        lg = (lg > 0.f) ? lg : 0.2f * lg;
        float ps = __expf(fminf(lg, 60.f));
        ss += ps;
        if (act) {
            uint4 u = *(const uint4*)&h[(size_t)wid * CH + c0];
            ac0 += ps * __uint_as_float((u.x & 0xffffu) << 16);
            ac1 += ps * __uint_as_float(u.x & 0xffff0000u);
            ac2 += ps * __uint_as_float((u.y & 0xffffu) << 16);
            ac3 += ps * __uint_as_float(u.y & 0xffff0000u);
            ac4 += ps * __uint_as_float((u.z & 0xffffu) << 16);
            ac5 += ps * __uint_as_float(u.z & 0xffff0000u);
            ac6 += ps * __uint_as_float((u.w & 0xffffu) << 16);
            ac7 += ps * __uint_as_float(u.w & 0xffff0000u);
        }
    }

    float inv = 1.f / (ss + 1e-16f);
    float4 bv0 = make_float4(0.f, 0.f, 0.f, 0.f), bv1 = bv0;
    if (act) {
        bv0 = *(const float4*)&bias[c0];
        bv1 = *(const float4*)&bias[c0 + 4];
    }
    float v0 = ac0 * inv + bv0.x;
    float v1 = ac1 * inv + bv0.y;
    float v2 = ac2 * inv + bv0.z;
    float v3 = ac3 * inv + bv0.w;
    float v4 = ac4 * inv + bv1.x;
    float v5 = ac5 * inv + bv1.y;
    float v6 = ac6 * inv + bv1.z;
    float v7 = ac7 * inv + bv1.w;

    if (BNP) {
        // block-level BN partials: 4 nodes/block -> psum/psq[block][ch]
        if (eslot == 0) {
            lsv[w][c0 + 0] = v0; lsv[w][c0 + 1] = v1;
            lsv[w][c0 + 2] = v2; lsv[w][c0 + 3] = v3;
            lsv[w][c0 + 4] = v4; lsv[w][c0 + 5] = v5;
            lsv[w][c0 + 6] = v6; lsv[w][c0 + 7] = v7;
        }
        __syncthreads();
        if (tid < 64) {
            float a0 = lsv[0][tid], a1 = lsv[1][tid], a2 = lsv[2][tid], a3 = lsv[3][tid];
            psum[(size_t)blockIdx.x * 64 + tid] = (a0 + a1) + (a2 + a3);
            psq[(size_t)blockIdx.x * 64 + tid]  = (a0 * a0 + a1 * a1) + (a2 * a2 + a3 * a3);
        }
    }

    if (LSM) {
        float mx = act ? fmaxf(fmaxf(fmaxf(v0, v1), fmaxf(v2, v3)),
                               fmaxf(fmaxf(v4, v5), fmaxf(v6, v7))) : -INFINITY;
        for (int o = 4; o >= 1; o >>= 1) mx = fmaxf(mx, __shfl_xor(mx, o));
        float sse = 0.f;
        if (act)
            sse = __expf(v0 - mx) + __expf(v1 - mx) + __expf(v2 - mx) + __expf(v3 - mx)
                + __expf(v4 - mx) + __expf(v5 - mx) + __expf(v6 - mx) + __expf(v7 - mx);
        for (int o = 4; o >= 1; o >>= 1) sse += __shfl_xor(sse, o);
        float ls = logf(sse);
        if (eslot == 0 && act) {
            *(float4*)&out[(size_t)wid * CH + c0] =
                make_float4(v0 - mx - ls, v1 - mx - ls, v2 - mx - ls, v3 - mx - ls);
            *(float4*)&out[(size_t)wid * CH + c0 + 4] =
                make_float4(v4 - mx - ls, v5 - mx - ls, v6 - mx - ls, v7 - mx - ls);
            *(float4*)&out[(size_t)n * CH + (size_t)wid * CH + c0] =
                make_float4(v0, v1, v2, v3);
            *(float4*)&out[(size_t)n * CH + (size_t)wid * CH + c0 + 4] =
                make_float4(v4, v5, v6, v7);
        }
    } else {
        if (eslot == 0 && act) {
            *(float4*)&out[(size_t)wid * CH + c0] = make_float4(v0, v1, v2, v3);
            *(float4*)&out[(size_t)wid * CH + c0 + 4] = make_float4(v4, v5, v6, v7);
        }
    }
}

// ---------------- BN reduce: 64 blocks (one per channel), deterministic ----------------
__global__ __launch_bounds__(256) void bn_reduce(
    const float* __restrict__ psum, const float* __restrict__ psq,
    const float* __restrict__ g, const float* __restrict__ bt,
    float* __restrict__ sc, float* __restrict__ sh, int nb, int n)
{
    int c = blockIdx.x;
    int t = threadIdx.x;
    float s = 0.f, s2 = 0.f;
    for (int r = t; r < nb; r += 256) {      // fixed order per thread
        s  += psum[(size_t)r * 64 + c];
        s2 += psq[(size_t)r * 64 + c];
    }
    __shared__ float a[256], b[256];
    a[t] = s; b[t] = s2; __syncthreads();
    for (int o = 128; o >= 1; o >>= 1) {     // fixed tree
        if (t < o) { a[t] += a[t + o]; b[t] += b[t + o]; }
        __syncthreads();
    }
    if (t == 0) {
        float mean = a[0] / n;
        float var = b[0] / n - mean * mean;   // biased, matches torch BN
        float invs = rsqrtf(var + 1e-5f);
        float scale = g[c] * invs;
        sc[c] = scale;
        sh[c] = bt[c] - mean * scale;
    }
}

extern "C" void kernel_launch(void* const* d_in, const int* in_sizes, int n_in,
                              void* d_out, int out_size, void* d_ws, size_t ws_size,
                              hipStream_t stream) {
    const float* x   = (const float*)d_in[0];
    const int*   ei  = (const int*)d_in[1];
    const float* W0  = (const float*)d_in[2];
    const float* as0 = (const float*)d_in[3];
    const float* ad0 = (const float*)d_in[4];
    const float* b0  = (const float*)d_in[5];
    const float* W1  = (const float*)d_in[6];
    const float* as1 = (const float*)d_in[7];
    const float* ad1 = (const float*)d_in[8];
    const float* b1  = (const float*)d_in[9];
    const float* W2  = (const float*)d_in[10];
    const float* as2 = (const float*)d_in[11];
    const float* ad2 = (const float*)d_in[12];
    const float* b2  = (const float*)d_in[13];
    const float* g0  = (const float*)d_in[14];
    const float* bt0 = (const float*)d_in[15];
    const float* g1  = (const float*)d_in[16];
    const float* bt1 = (const float*)d_in[17];

    const int* esrc = ei;
    const int* edst = ei + NE;

    char* ws = (char*)d_ws;
    size_t off = 0;
    auto alloc = [&](size_t bytes) {
        void* p = ws + off;
        off += (bytes + 255) & ~(size_t)255;
        return p;
    };
    int* cnt      = (int*)alloc((size_t)NN * CURPAD * 4);
    unsigned* pk2 = (unsigned*)alloc((size_t)NN * CAP * 4);
    ushort* hbuf  = (ushort*)alloc((size_t)NN * 64 * 2);
    float* obuf   = (float*)alloc((size_t)NN * 64 * 4);
    float* asb    = (float*)alloc((size_t)NN * 4 * 4);
    float* adb    = (float*)alloc((size_t)NN * 4 * 4);
    float* psum   = (float*)alloc((size_t)(NN / 4) * 64 * 4);
    float* psq    = (float*)alloc((size_t)(NN / 4) * 64 * 4);
    float* sc     = (float*)alloc(64 * 4);
    float* sh     = (float*)alloc(64 * 4);

    const int SCB = (NE + 2047) / 2048;          // 391 scatter blocks
    const int GBM = (NN + 63) / 64;              // 782 gemm blocks
    const int GB4 = NN / 4;                      // 12500 gat blocks (NN % 4 == 0)

    // zero cursors, then fused {slot scatter (first) ∥ gemm0}
    hipMemsetAsync(cnt, 0, (size_t)NN * CURPAD * 4, stream);
    mfma_gemm<128, 4, 64, 4, true><<<SCB + GBM, 256, 0, stream>>>(
        x, W0, as0, ad0, nullptr, nullptr, hbuf, asb, adb, NN, SCB,
        esrc, edst, cnt, pk2);

    // Layer 0 aggregation + BN0 partials
    gat_kernel<64, 4, false, true><<<GB4, 256, 0, stream>>>(
        hbuf, asb, adb, cnt, pk2, b0, obuf, psum, psq, NN);
    bn_reduce<<<64, 256, 0, stream>>>(psum, psq, g0, bt0, sc, sh, GB4, NN);

    // Layer 1 (BN0 fused into A-load)
    mfma_gemm<64, 4, 64, 4, false><<<GBM, 256, 0, stream>>>(
        obuf, W1, as1, ad1, sc, sh, hbuf, asb, adb, NN, 0,
        nullptr, nullptr, nullptr, nullptr);
    gat_kernel<64, 4, false, true><<<GB4, 256, 0, stream>>>(
        hbuf, asb, adb, cnt, pk2, b1, obuf, psum, psq, NN);
    bn_reduce<<<64, 256, 0, stream>>>(psum, psq, g1, bt1, sc, sh, GB4, NN);

    // Layer 2 (BN1 fused into A-load); log_softmax fused in gat epilogue
    mfma_gemm<64, 3, 40, 1, false><<<GBM, 256, 0, stream>>>(
        obuf, W2, as2, ad2, sc, sh, hbuf, asb, adb, NN, 0,
        nullptr, nullptr, nullptr, nullptr);
    gat_kernel<40, 1, true, false><<<GB4, 256, 0, stream>>>(
        hbuf, asb, adb, cnt, pk2, b2, (float*)d_out, nullptr, nullptr, NN);
}